// Round 4
// baseline (520.954 us; speedup 1.0000x reference)
//
#include <hip/hip_runtime.h>

#define B_ 4
#define T_ 4096
#define C_ 1024
#define H_ 128

typedef __attribute__((ext_vector_type(8))) __bf16 bf16x8;
typedef __attribute__((ext_vector_type(8))) unsigned short u16x8;
typedef __attribute__((ext_vector_type(4))) float f32x4;

__device__ __forceinline__ unsigned short f2bf(float f) {
  unsigned int u = __float_as_uint(f);
  return (unsigned short)((u + 0x7FFFu + ((u >> 16) & 1u)) >> 16);
}
__device__ __forceinline__ float bf2f(unsigned short h) {
  return __uint_as_float((unsigned)h << 16);
}
__device__ __forceinline__ bf16x8 ldb8(const unsigned short* p) {
  return *(const bf16x8*)(const void*)p;
}
// load 8 fp32, emit hi/lo bf16x8 fragments (hi+lo error ~2^-18 rel)
__device__ __forceinline__ void split8(const float* p, bf16x8& hi, bf16x8& lo) {
  float f[8];
  *(f32x4*)&f[0] = *(const f32x4*)(const void*)p;
  *(f32x4*)&f[4] = *(const f32x4*)(const void*)(p + 4);
  u16x8 h, l;
#pragma unroll
  for (int j = 0; j < 8; j++) {
    h[j] = f2bf(f[j]);
    l[j] = f2bf(f[j] - bf2f(h[j]));
  }
  hi = __builtin_bit_cast(bf16x8, h);
  lo = __builtin_bit_cast(bf16x8, l);
}

// ---------------------------------------------------------------------------
// Kernel 1: W [C][H] fp32 (x3) -> Wthi/Wtlo [.][H][C] bf16 (transpose + split)
// ---------------------------------------------------------------------------
__global__ void wt_k(const float* __restrict__ Wq, const float* __restrict__ Wk,
                     const float* __restrict__ Wv, unsigned short* __restrict__ Whi,
                     unsigned short* __restrict__ Wlo) {
  __shared__ float tile[32][33];
  int m = blockIdx.z;
  const float* W = (m == 0) ? Wq : ((m == 1) ? Wk : Wv);
  int c0 = blockIdx.x * 32, h0 = blockIdx.y * 32;
  int tx = threadIdx.x, ty = threadIdx.y;  // 32 x 8
#pragma unroll
  for (int i = 0; i < 4; i++)
    tile[ty + 8 * i][tx] = W[(size_t)(c0 + ty + 8 * i) * H_ + h0 + tx];
  __syncthreads();
  size_t base = (size_t)m * H_ * C_;
#pragma unroll
  for (int i = 0; i < 4; i++) {
    float f = tile[tx][ty + 8 * i];
    unsigned short hi = f2bf(f);
    size_t idx = base + (size_t)(h0 + ty + 8 * i) * C_ + c0 + tx;
    Whi[idx] = hi;
    if (m < 2) Wlo[idx] = f2bf(f - bf2f(hi));
  }
}

// ---------------------------------------------------------------------------
// Kernel 2: fused QKV projection, split-bf16 precision for Q,K.
// Writes Q,K PRE-SPLIT (Qhi/Qlo/Khi/Klo bf16 [B*T][H]); V transposed bf16.
// ---------------------------------------------------------------------------
#define WP 40  // LDS pitch: keeps ds_read_b128 at the free 2-way bank pattern
__global__ __launch_bounds__(256) void qkv_k(
    const float* __restrict__ x, const unsigned short* __restrict__ Whi,
    const unsigned short* __restrict__ Wlo, unsigned short* __restrict__ Qhi,
    unsigned short* __restrict__ Qlo, unsigned short* __restrict__ Khi,
    unsigned short* __restrict__ Klo, unsigned short* __restrict__ Vt) {
  int m = blockIdx.x % 3;
  int r0 = (blockIdx.x / 3) * 64;
  __shared__ unsigned short whi[128 * WP];
  __shared__ unsigned short wlo[128 * WP];
  int tid = threadIdx.x;
  int lane = tid & 63, wave = tid >> 6;
  int l15 = lane & 15, quad = lane >> 4;
  const unsigned short* Wmh = Whi + (size_t)m * H_ * C_;
  const unsigned short* Wml = Wlo + (size_t)m * H_ * C_;
  f32x4 acc[8];
#pragma unroll
  for (int n = 0; n < 8; n++) acc[n] = (f32x4){0.f, 0.f, 0.f, 0.f};
  int wrow = r0 + wave * 16 + l15;  // A-fragment row for this lane
  const float* xrow = x + (size_t)wrow * C_;

  for (int k0 = 0; k0 < C_; k0 += 32) {
    __syncthreads();
#pragma unroll
    for (int it = 0; it < 2; it++) {
      int c = it * 256 + tid;
      int h = c >> 2, kc = c & 3;
      *(int4*)(void*)(whi + h * WP + kc * 8) =
          *(const int4*)(const void*)(Wmh + (size_t)h * C_ + k0 + kc * 8);
      if (m < 2)
        *(int4*)(void*)(wlo + h * WP + kc * 8) =
            *(const int4*)(const void*)(Wml + (size_t)h * C_ + k0 + kc * 8);
    }
    __syncthreads();
    bf16x8 ahi, alo;
    split8(xrow + k0 + quad * 8, ahi, alo);
    if (m < 2) {
#pragma unroll
      for (int n = 0; n < 8; n++) {
        bf16x8 bhi = ldb8(whi + (n * 16 + l15) * WP + quad * 8);
        bf16x8 blo = ldb8(wlo + (n * 16 + l15) * WP + quad * 8);
        acc[n] = __builtin_amdgcn_mfma_f32_16x16x32_bf16(ahi, bhi, acc[n], 0, 0, 0);
        acc[n] = __builtin_amdgcn_mfma_f32_16x16x32_bf16(alo, bhi, acc[n], 0, 0, 0);
        acc[n] = __builtin_amdgcn_mfma_f32_16x16x32_bf16(ahi, blo, acc[n], 0, 0, 0);
      }
    } else {
#pragma unroll
      for (int n = 0; n < 8; n++) {
        bf16x8 bhi = ldb8(whi + (n * 16 + l15) * WP + quad * 8);
        acc[n] = __builtin_amdgcn_mfma_f32_16x16x32_bf16(ahi, bhi, acc[n], 0, 0, 0);
      }
    }
  }
  int ob = r0 + wave * 16 + quad * 4;
  if (m < 2) {
    unsigned short* Oh = (m == 0) ? Qhi : Khi;
    unsigned short* Ol = (m == 0) ? Qlo : Klo;
#pragma unroll
    for (int n = 0; n < 8; n++)
#pragma unroll
      for (int r = 0; r < 4; r++) {
        float f = acc[n][r];
        unsigned short hi = f2bf(f);
        size_t idx = (size_t)(ob + r) * H_ + n * 16 + l15;
        Oh[idx] = hi;
        Ol[idx] = f2bf(f - bf2f(hi));
      }
  } else {
#pragma unroll
    for (int n = 0; n < 8; n++)
#pragma unroll
      for (int r = 0; r < 4; r++) {
        int gr = ob + r;
        int bb = gr >> 12, t = gr & (T_ - 1);
        Vt[((size_t)bb * H_ + n * 16 + l15) * T_ + t] = f2bf(acc[n][r]);
      }
  }
}

// ---------------------------------------------------------------------------
// Kernel 3: flash attention, SPLIT-KV: 4 waves per block share one 16-row
// Q-tile; wave w handles kv-tiles kt = w, w+4, ... with private (o,m,l);
// two-barrier LDS combine merges partials. 4 blocks/CU -> 4 waves/SIMD
// (was 1 wave/SIMD: pure latency exposure, MfmaUtil 5.5%).
// ---------------------------------------------------------------------------
#define PP 72   // per-wave P-buffer pitch (u16): 2-way-free for b128 reads
#define OP 132  // combine buffer pitch (f32): quads land 2-way-free
__global__ __launch_bounds__(256, 4) void flash_k(
    const unsigned short* __restrict__ Qhi, const unsigned short* __restrict__ Qlo,
    const unsigned short* __restrict__ Khi, const unsigned short* __restrict__ Klo,
    const unsigned short* __restrict__ Vt, float* __restrict__ out) {
  __shared__ __align__(16) unsigned char smem[64 * OP * 4];  // 33792 B
  __shared__ float2 mlbuf[64];
  int tid = threadIdx.x;
  int wave = tid >> 6, lane = tid & 63;
  int l15 = lane & 15, quad = lane >> 4;
  unsigned short* pbuf = (unsigned short*)smem + wave * 16 * PP;  // wave-private
  float* obuf = (float*)(void*)smem;

  // XCD-affine mapping: batch = (blockIdx&7)>>1; longest q-tiles first (LPT)
  int g = blockIdx.x & 7;
  int j = blockIdx.x >> 3;  // 0..127
  int b = g >> 1;
  int i = 255 - (2 * j + (g & 1));
  int q0 = i * 16;
  size_t boff = (size_t)b * T_ * H_;
  const unsigned short* Khb = Khi + boff;
  const unsigned short* Klb = Klo + boff;
  const unsigned short* Vb = Vt + (size_t)b * H_ * T_;

  bf16x8 qh[4], ql[4];
  {
    const unsigned short* qrh = Qhi + boff + (size_t)(q0 + l15) * H_ + quad * 8;
    const unsigned short* qrl = Qlo + boff + (size_t)(q0 + l15) * H_ + quad * 8;
#pragma unroll
    for (int kk = 0; kk < 4; kk++) {
      qh[kk] = ldb8(qrh + kk * 32);
      ql[kk] = ldb8(qrl + kk * 32);
    }
  }
  f32x4 o[8];
#pragma unroll
  for (int n = 0; n < 8; n++) o[n] = (f32x4){0.f, 0.f, 0.f, 0.f};
  float mr[4] = {-1e30f, -1e30f, -1e30f, -1e30f};
  float lr[4] = {0.f, 0.f, 0.f, 0.f};

  int ktd = q0 >> 6;  // diagonal (masked) tile index
  for (int kt = wave; kt <= ktd; kt += 4) {
    f32x4 s[4];
#pragma unroll
    for (int n = 0; n < 4; n++) s[n] = (f32x4){0.f, 0.f, 0.f, 0.f};
#pragma unroll
    for (int n = 0; n < 4; n++) {
      size_t ro = (size_t)(kt * 64 + n * 16 + l15) * H_ + quad * 8;
      bf16x8 kh[4], kl[4];
#pragma unroll
      for (int kk = 0; kk < 4; kk++) {
        kh[kk] = ldb8(Khb + ro + kk * 32);
        kl[kk] = ldb8(Klb + ro + kk * 32);
      }
#pragma unroll
      for (int kk = 0; kk < 4; kk++) {
        s[n] = __builtin_amdgcn_mfma_f32_16x16x32_bf16(qh[kk], kh[kk], s[n], 0, 0, 0);
        s[n] = __builtin_amdgcn_mfma_f32_16x16x32_bf16(ql[kk], kh[kk], s[n], 0, 0, 0);
        s[n] = __builtin_amdgcn_mfma_f32_16x16x32_bf16(qh[kk], kl[kk], s[n], 0, 0, 0);
      }
    }
    // prefetch V; softmax VALU hides the latency
    bf16x8 vf[2][8];
#pragma unroll
    for (int ks = 0; ks < 2; ks++)
#pragma unroll
      for (int n = 0; n < 8; n++)
        vf[ks][n] = ldb8(Vb + (size_t)(n * 16 + l15) * T_ + kt * 64 + ks * 32 + quad * 8);
    if (kt == ktd) {
#pragma unroll
      for (int n = 0; n < 4; n++) {
        int col = kt * 64 + n * 16 + l15;
#pragma unroll
        for (int r = 0; r < 4; r++) {
          int row = q0 + quad * 4 + r;
          if (col > row) s[n][r] = -1e30f;
        }
      }
    }
    float mnew[4];
#pragma unroll
    for (int r = 0; r < 4; r++)
      mnew[r] = fmaxf(fmaxf(s[0][r], s[1][r]), fmaxf(s[2][r], s[3][r]));
#pragma unroll
    for (int off = 1; off < 16; off <<= 1)
#pragma unroll
      for (int r = 0; r < 4; r++) mnew[r] = fmaxf(mnew[r], __shfl_xor(mnew[r], off));
    float alpha[4];
#pragma unroll
    for (int r = 0; r < 4; r++) {
      float mi = fmaxf(mr[r], mnew[r]);
      alpha[r] = __expf(mr[r] - mi);
      mr[r] = mi;
    }
    float p[4][4], rs[4];
#pragma unroll
    for (int n = 0; n < 4; n++)
#pragma unroll
      for (int r = 0; r < 4; r++) p[n][r] = __expf(s[n][r] - mr[r]);
#pragma unroll
    for (int r = 0; r < 4; r++) rs[r] = (p[0][r] + p[1][r]) + (p[2][r] + p[3][r]);
#pragma unroll
    for (int off = 1; off < 16; off <<= 1)
#pragma unroll
      for (int r = 0; r < 4; r++) rs[r] += __shfl_xor(rs[r], off);
#pragma unroll
    for (int r = 0; r < 4; r++) lr[r] = lr[r] * alpha[r] + rs[r];
#pragma unroll
    for (int n = 0; n < 8; n++)
#pragma unroll
      for (int r = 0; r < 4; r++) o[n][r] *= alpha[r];
    // P: C-layout -> A-layout via wave-private LDS (lgkm ordering suffices)
    asm volatile("s_waitcnt lgkmcnt(0)" ::: "memory");
#pragma unroll
    for (int n = 0; n < 4; n++)
#pragma unroll
      for (int r = 0; r < 4; r++)
        pbuf[(quad * 4 + r) * PP + n * 16 + l15] = f2bf(p[n][r]);
    asm volatile("s_waitcnt lgkmcnt(0)" ::: "memory");
#pragma unroll
    for (int ks = 0; ks < 2; ks++) {
      bf16x8 pa = ldb8(pbuf + l15 * PP + ks * 32 + quad * 8);
#pragma unroll
      for (int n = 0; n < 8; n++)
        o[n] = __builtin_amdgcn_mfma_f32_16x16x32_bf16(pa, vf[ks][n], o[n], 0, 0, 0);
    }
  }

  // ---- cross-wave combine ----
  if (l15 == 0) {
#pragma unroll
    for (int r = 0; r < 4; r++)
      mlbuf[wave * 16 + quad * 4 + r] = make_float2(mr[r], lr[r]);
  }
  __syncthreads();
  // scale own partial by exp(m_w - M) and stage to obuf
  float f[4];
#pragma unroll
  for (int r = 0; r < 4; r++) {
    int row = quad * 4 + r;
    float M = mlbuf[row].x;
#pragma unroll
    for (int w2 = 1; w2 < 4; w2++) M = fmaxf(M, mlbuf[w2 * 16 + row].x);
    f[r] = __expf(mr[r] - M);
  }
#pragma unroll
  for (int n = 0; n < 8; n++)
#pragma unroll
    for (int r = 0; r < 4; r++)
      obuf[(size_t)(wave * 16 + quad * 4 + r) * OP + n * 16 + l15] = o[n][r] * f[r];
  __syncthreads();
  // sum 4 partials; wave w owns rows w*4..w*4+3
  int row = wave * 4 + quad;
  int c0 = l15 * 8;
  float M = mlbuf[row].x;
#pragma unroll
  for (int w2 = 1; w2 < 4; w2++) M = fmaxf(M, mlbuf[w2 * 16 + row].x);
  float L = 0.f;
#pragma unroll
  for (int w2 = 0; w2 < 4; w2++)
    L += __expf(mlbuf[w2 * 16 + row].x - M) * mlbuf[w2 * 16 + row].y;
  f32x4 a0 = (f32x4){0.f, 0.f, 0.f, 0.f}, a1 = a0;
#pragma unroll
  for (int w2 = 0; w2 < 4; w2++) {
    const float* src = obuf + (size_t)(w2 * 16 + row) * OP + c0;
    a0 += *(const f32x4*)(const void*)src;
    a1 += *(const f32x4*)(const void*)(src + 4);
  }
  float invL = 1.0f / L;
  float* op = out + ((size_t)b * T_ + q0 + row) * H_ + c0;
  *(f32x4*)(void*)op = a0 * invL;
  *(f32x4*)(void*)(op + 4) = a1 * invL;
}

// ---------------------------------------------------------------------------
extern "C" void kernel_launch(void* const* d_in, const int* in_sizes, int n_in,
                              void* d_out, int out_size, void* d_ws, size_t ws_size,
                              hipStream_t stream) {
  const float* x  = (const float*)d_in[0];
  const float* Wq = (const float*)d_in[1];
  const float* Wk = (const float*)d_in[2];
  const float* Wv = (const float*)d_in[3];
  const size_t BTH = (size_t)B_ * T_ * H_;
  unsigned short* Whi = (unsigned short*)d_ws;   // 3*H*C
  unsigned short* Wlo = Whi + 3 * H_ * C_;       // 2*H*C (Q,K only)
  unsigned short* Vt  = Wlo + 2 * H_ * C_;       // BTH
  unsigned short* Qhi = Vt + BTH;
  unsigned short* Qlo = Qhi + BTH;
  unsigned short* Khi = Qlo + BTH;
  unsigned short* Klo = Khi + BTH;
  float* out = (float*)d_out;

  wt_k<<<dim3(32, 4, 3), dim3(32, 8), 0, stream>>>(Wq, Wk, Wv, Whi, Wlo);
  qkv_k<<<3 * (B_ * T_ / 64), 256, 0, stream>>>(x, Whi, Wlo, Qhi, Qlo, Khi, Klo, Vt);
  flash_k<<<B_ * (T_ / 16), 256, 0, stream>>>(Qhi, Qlo, Khi, Klo, Vt, out);
}

// Round 5
// 394.693 us; speedup vs baseline: 1.3199x; 1.3199x over previous
//
#include <hip/hip_runtime.h>

#define B_ 4
#define T_ 4096
#define C_ 1024
#define H_ 128

typedef __attribute__((ext_vector_type(8))) __bf16 bf16x8;
typedef __attribute__((ext_vector_type(8))) unsigned short u16x8;
typedef __attribute__((ext_vector_type(4))) float f32x4;

__device__ __forceinline__ unsigned short f2bf(float f) {
  unsigned int u = __float_as_uint(f);
  return (unsigned short)((u + 0x7FFFu + ((u >> 16) & 1u)) >> 16);
}
__device__ __forceinline__ float bf2f(unsigned short h) {
  return __uint_as_float((unsigned)h << 16);
}
__device__ __forceinline__ bf16x8 ldb8(const unsigned short* p) {
  return *(const bf16x8*)(const void*)p;
}
// load 8 fp32, emit hi/lo bf16x8 fragments (hi+lo error ~2^-18 rel)
__device__ __forceinline__ void split8(const float* p, bf16x8& hi, bf16x8& lo) {
  float f[8];
  *(f32x4*)&f[0] = *(const f32x4*)(const void*)p;
  *(f32x4*)&f[4] = *(const f32x4*)(const void*)(p + 4);
  u16x8 h, l;
#pragma unroll
  for (int j = 0; j < 8; j++) {
    h[j] = f2bf(f[j]);
    l[j] = f2bf(f[j] - bf2f(h[j]));
  }
  hi = __builtin_bit_cast(bf16x8, h);
  lo = __builtin_bit_cast(bf16x8, l);
}

// ---------------------------------------------------------------------------
// Kernel 1: W [C][H] fp32 (x3) -> Wthi/Wtlo [.][H][C] bf16 (transpose + split)
// ---------------------------------------------------------------------------
__global__ void wt_k(const float* __restrict__ Wq, const float* __restrict__ Wk,
                     const float* __restrict__ Wv, unsigned short* __restrict__ Whi,
                     unsigned short* __restrict__ Wlo) {
  __shared__ float tile[32][33];
  int m = blockIdx.z;
  const float* W = (m == 0) ? Wq : ((m == 1) ? Wk : Wv);
  int c0 = blockIdx.x * 32, h0 = blockIdx.y * 32;
  int tx = threadIdx.x, ty = threadIdx.y;  // 32 x 8
#pragma unroll
  for (int i = 0; i < 4; i++)
    tile[ty + 8 * i][tx] = W[(size_t)(c0 + ty + 8 * i) * H_ + h0 + tx];
  __syncthreads();
  size_t base = (size_t)m * H_ * C_;
#pragma unroll
  for (int i = 0; i < 4; i++) {
    float f = tile[tx][ty + 8 * i];
    unsigned short hi = f2bf(f);
    size_t idx = base + (size_t)(h0 + ty + 8 * i) * C_ + c0 + tx;
    Whi[idx] = hi;
    if (m < 2) Wlo[idx] = f2bf(f - bf2f(hi));
  }
}

// ---------------------------------------------------------------------------
// Kernel 2: fused QKV projection, split-bf16 precision for Q,K.
// Writes Q,K PRE-SPLIT (Qhi/Qlo/Khi/Klo bf16 [B*T][H]); V transposed bf16.
// ---------------------------------------------------------------------------
#define WP 40  // LDS pitch: keeps ds_read_b128 at the free 2-way bank pattern
__global__ __launch_bounds__(256) void qkv_k(
    const float* __restrict__ x, const unsigned short* __restrict__ Whi,
    const unsigned short* __restrict__ Wlo, unsigned short* __restrict__ Qhi,
    unsigned short* __restrict__ Qlo, unsigned short* __restrict__ Khi,
    unsigned short* __restrict__ Klo, unsigned short* __restrict__ Vt) {
  int m = blockIdx.x % 3;
  int r0 = (blockIdx.x / 3) * 64;
  __shared__ unsigned short whi[128 * WP];
  __shared__ unsigned short wlo[128 * WP];
  int tid = threadIdx.x;
  int lane = tid & 63, wave = tid >> 6;
  int l15 = lane & 15, quad = lane >> 4;
  const unsigned short* Wmh = Whi + (size_t)m * H_ * C_;
  const unsigned short* Wml = Wlo + (size_t)m * H_ * C_;
  f32x4 acc[8];
#pragma unroll
  for (int n = 0; n < 8; n++) acc[n] = (f32x4){0.f, 0.f, 0.f, 0.f};
  int wrow = r0 + wave * 16 + l15;  // A-fragment row for this lane
  const float* xrow = x + (size_t)wrow * C_;

  for (int k0 = 0; k0 < C_; k0 += 32) {
    __syncthreads();
#pragma unroll
    for (int it = 0; it < 2; it++) {
      int c = it * 256 + tid;
      int h = c >> 2, kc = c & 3;
      *(int4*)(void*)(whi + h * WP + kc * 8) =
          *(const int4*)(const void*)(Wmh + (size_t)h * C_ + k0 + kc * 8);
      if (m < 2)
        *(int4*)(void*)(wlo + h * WP + kc * 8) =
            *(const int4*)(const void*)(Wml + (size_t)h * C_ + k0 + kc * 8);
    }
    __syncthreads();
    bf16x8 ahi, alo;
    split8(xrow + k0 + quad * 8, ahi, alo);
    if (m < 2) {
#pragma unroll
      for (int n = 0; n < 8; n++) {
        bf16x8 bhi = ldb8(whi + (n * 16 + l15) * WP + quad * 8);
        bf16x8 blo = ldb8(wlo + (n * 16 + l15) * WP + quad * 8);
        acc[n] = __builtin_amdgcn_mfma_f32_16x16x32_bf16(ahi, bhi, acc[n], 0, 0, 0);
        acc[n] = __builtin_amdgcn_mfma_f32_16x16x32_bf16(alo, bhi, acc[n], 0, 0, 0);
        acc[n] = __builtin_amdgcn_mfma_f32_16x16x32_bf16(ahi, blo, acc[n], 0, 0, 0);
      }
    } else {
#pragma unroll
      for (int n = 0; n < 8; n++) {
        bf16x8 bhi = ldb8(whi + (n * 16 + l15) * WP + quad * 8);
        acc[n] = __builtin_amdgcn_mfma_f32_16x16x32_bf16(ahi, bhi, acc[n], 0, 0, 0);
      }
    }
  }
  int ob = r0 + wave * 16 + quad * 4;
  if (m < 2) {
    unsigned short* Oh = (m == 0) ? Qhi : Khi;
    unsigned short* Ol = (m == 0) ? Qlo : Klo;
#pragma unroll
    for (int n = 0; n < 8; n++)
#pragma unroll
      for (int r = 0; r < 4; r++) {
        float f = acc[n][r];
        unsigned short hi = f2bf(f);
        size_t idx = (size_t)(ob + r) * H_ + n * 16 + l15;
        Oh[idx] = hi;
        Ol[idx] = f2bf(f - bf2f(hi));
      }
  } else {
#pragma unroll
    for (int n = 0; n < 8; n++)
#pragma unroll
      for (int r = 0; r < 4; r++) {
        int gr = ob + r;
        int bb = gr >> 12, t = gr & (T_ - 1);
        Vt[((size_t)bb * H_ + n * 16 + l15) * T_ + t] = f2bf(acc[n][r]);
      }
  }
}

// ---------------------------------------------------------------------------
// Kernel 3: flash attention, SPLIT-KV: 4 waves per block share one 16-row
// Q-tile; wave w handles kv-tiles kt = w, w+4, ...; LDS combine at the end.
// __launch_bounds__(256,3): 170 VGPR cap — round 4's (256,4)=128 cap forced
// scratch spills (VGPR 64, WRITE_SIZE 661MB). Body needs ~116+32acc regs.
// ---------------------------------------------------------------------------
#define PP 72   // per-wave P-buffer pitch (u16): 2-way-free for b128 reads
#define OP 132  // combine buffer pitch (f32): quads land 2-way-free
__global__ __launch_bounds__(256, 3) void flash_k(
    const unsigned short* __restrict__ Qhi, const unsigned short* __restrict__ Qlo,
    const unsigned short* __restrict__ Khi, const unsigned short* __restrict__ Klo,
    const unsigned short* __restrict__ Vt, float* __restrict__ out) {
  __shared__ __align__(16) unsigned char smem[64 * OP * 4];  // 33792 B
  __shared__ float2 mlbuf[64];
  int tid = threadIdx.x;
  int wave = tid >> 6, lane = tid & 63;
  int l15 = lane & 15, quad = lane >> 4;
  unsigned short* pbuf = (unsigned short*)smem + wave * 16 * PP;  // wave-private
  float* obuf = (float*)(void*)smem;

  // XCD-affine mapping: batch = (blockIdx&7)>>1; longest q-tiles first (LPT)
  int g = blockIdx.x & 7;
  int j = blockIdx.x >> 3;  // 0..127
  int b = g >> 1;
  int i = 255 - (2 * j + (g & 1));
  int q0 = i * 16;
  size_t boff = (size_t)b * T_ * H_;
  const unsigned short* Khb = Khi + boff;
  const unsigned short* Klb = Klo + boff;
  const unsigned short* Vb = Vt + (size_t)b * H_ * T_;

  bf16x8 qh[4], ql[4];
  {
    const unsigned short* qrh = Qhi + boff + (size_t)(q0 + l15) * H_ + quad * 8;
    const unsigned short* qrl = Qlo + boff + (size_t)(q0 + l15) * H_ + quad * 8;
#pragma unroll
    for (int kk = 0; kk < 4; kk++) {
      qh[kk] = ldb8(qrh + kk * 32);
      ql[kk] = ldb8(qrl + kk * 32);
    }
  }
  f32x4 o[8];
#pragma unroll
  for (int n = 0; n < 8; n++) o[n] = (f32x4){0.f, 0.f, 0.f, 0.f};
  float mr[4] = {-1e30f, -1e30f, -1e30f, -1e30f};
  float lr[4] = {0.f, 0.f, 0.f, 0.f};

  int ktd = q0 >> 6;  // diagonal (masked) tile index
  for (int kt = wave; kt <= ktd; kt += 4) {
    f32x4 s[4];
#pragma unroll
    for (int n = 0; n < 4; n++) s[n] = (f32x4){0.f, 0.f, 0.f, 0.f};
#pragma unroll
    for (int n = 0; n < 4; n++) {
      size_t ro = (size_t)(kt * 64 + n * 16 + l15) * H_ + quad * 8;
      bf16x8 kh[4], kl[4];
#pragma unroll
      for (int kk = 0; kk < 4; kk++) {
        kh[kk] = ldb8(Khb + ro + kk * 32);
        kl[kk] = ldb8(Klb + ro + kk * 32);
      }
#pragma unroll
      for (int kk = 0; kk < 4; kk++) {
        s[n] = __builtin_amdgcn_mfma_f32_16x16x32_bf16(qh[kk], kh[kk], s[n], 0, 0, 0);
        s[n] = __builtin_amdgcn_mfma_f32_16x16x32_bf16(ql[kk], kh[kk], s[n], 0, 0, 0);
        s[n] = __builtin_amdgcn_mfma_f32_16x16x32_bf16(qh[kk], kl[kk], s[n], 0, 0, 0);
      }
    }
    // prefetch V; softmax VALU hides the latency
    bf16x8 vf[2][8];
#pragma unroll
    for (int ks = 0; ks < 2; ks++)
#pragma unroll
      for (int n = 0; n < 8; n++)
        vf[ks][n] = ldb8(Vb + (size_t)(n * 16 + l15) * T_ + kt * 64 + ks * 32 + quad * 8);
    if (kt == ktd) {
#pragma unroll
      for (int n = 0; n < 4; n++) {
        int col = kt * 64 + n * 16 + l15;
#pragma unroll
        for (int r = 0; r < 4; r++) {
          int row = q0 + quad * 4 + r;
          if (col > row) s[n][r] = -1e30f;
        }
      }
    }
    float mnew[4];
#pragma unroll
    for (int r = 0; r < 4; r++)
      mnew[r] = fmaxf(fmaxf(s[0][r], s[1][r]), fmaxf(s[2][r], s[3][r]));
#pragma unroll
    for (int off = 1; off < 16; off <<= 1)
#pragma unroll
      for (int r = 0; r < 4; r++) mnew[r] = fmaxf(mnew[r], __shfl_xor(mnew[r], off));
    float alpha[4];
#pragma unroll
    for (int r = 0; r < 4; r++) {
      float mi = fmaxf(mr[r], mnew[r]);
      alpha[r] = __expf(mr[r] - mi);
      mr[r] = mi;
    }
    float p[4][4], rs[4];
#pragma unroll
    for (int n = 0; n < 4; n++)
#pragma unroll
      for (int r = 0; r < 4; r++) p[n][r] = __expf(s[n][r] - mr[r]);
#pragma unroll
    for (int r = 0; r < 4; r++) rs[r] = (p[0][r] + p[1][r]) + (p[2][r] + p[3][r]);
#pragma unroll
    for (int off = 1; off < 16; off <<= 1)
#pragma unroll
      for (int r = 0; r < 4; r++) rs[r] += __shfl_xor(rs[r], off);
#pragma unroll
    for (int r = 0; r < 4; r++) lr[r] = lr[r] * alpha[r] + rs[r];
#pragma unroll
    for (int n = 0; n < 8; n++)
#pragma unroll
      for (int r = 0; r < 4; r++) o[n][r] *= alpha[r];
    // P: C-layout -> A-layout via wave-private LDS (lgkm ordering suffices)
    asm volatile("s_waitcnt lgkmcnt(0)" ::: "memory");
#pragma unroll
    for (int n = 0; n < 4; n++)
#pragma unroll
      for (int r = 0; r < 4; r++)
        pbuf[(quad * 4 + r) * PP + n * 16 + l15] = f2bf(p[n][r]);
    asm volatile("s_waitcnt lgkmcnt(0)" ::: "memory");
#pragma unroll
    for (int ks = 0; ks < 2; ks++) {
      bf16x8 pa = ldb8(pbuf + l15 * PP + ks * 32 + quad * 8);
#pragma unroll
      for (int n = 0; n < 8; n++)
        o[n] = __builtin_amdgcn_mfma_f32_16x16x32_bf16(pa, vf[ks][n], o[n], 0, 0, 0);
    }
  }

  // ---- cross-wave combine ----
  if (l15 == 0) {
#pragma unroll
    for (int r = 0; r < 4; r++)
      mlbuf[wave * 16 + quad * 4 + r] = make_float2(mr[r], lr[r]);
  }
  __syncthreads();
  // scale own partial by exp(m_w - M) and stage to obuf
  float f[4];
#pragma unroll
  for (int r = 0; r < 4; r++) {
    int row = quad * 4 + r;
    float M = mlbuf[row].x;
#pragma unroll
    for (int w2 = 1; w2 < 4; w2++) M = fmaxf(M, mlbuf[w2 * 16 + row].x);
    f[r] = __expf(mr[r] - M);
  }
#pragma unroll
  for (int n = 0; n < 8; n++)
#pragma unroll
    for (int r = 0; r < 4; r++)
      obuf[(size_t)(wave * 16 + quad * 4 + r) * OP + n * 16 + l15] = o[n][r] * f[r];
  __syncthreads();
  // sum 4 partials; wave w owns rows w*4..w*4+3
  int row = wave * 4 + quad;
  int c0 = l15 * 8;
  float M = mlbuf[row].x;
#pragma unroll
  for (int w2 = 1; w2 < 4; w2++) M = fmaxf(M, mlbuf[w2 * 16 + row].x);
  float L = 0.f;
#pragma unroll
  for (int w2 = 0; w2 < 4; w2++)
    L += __expf(mlbuf[w2 * 16 + row].x - M) * mlbuf[w2 * 16 + row].y;
  f32x4 a0 = (f32x4){0.f, 0.f, 0.f, 0.f}, a1 = a0;
#pragma unroll
  for (int w2 = 0; w2 < 4; w2++) {
    const float* src = obuf + (size_t)(w2 * 16 + row) * OP + c0;
    a0 += *(const f32x4*)(const void*)src;
    a1 += *(const f32x4*)(const void*)(src + 4);
  }
  float invL = 1.0f / L;
  float* op = out + ((size_t)b * T_ + q0 + row) * H_ + c0;
  *(f32x4*)(void*)op = a0 * invL;
  *(f32x4*)(void*)(op + 4) = a1 * invL;
}

// ---------------------------------------------------------------------------
extern "C" void kernel_launch(void* const* d_in, const int* in_sizes, int n_in,
                              void* d_out, int out_size, void* d_ws, size_t ws_size,
                              hipStream_t stream) {
  const float* x  = (const float*)d_in[0];
  const float* Wq = (const float*)d_in[1];
  const float* Wk = (const float*)d_in[2];
  const float* Wv = (const float*)d_in[3];
  const size_t BTH = (size_t)B_ * T_ * H_;
  unsigned short* Whi = (unsigned short*)d_ws;   // 3*H*C
  unsigned short* Wlo = Whi + 3 * H_ * C_;       // 2*H*C (Q,K only)
  unsigned short* Vt  = Wlo + 2 * H_ * C_;       // BTH
  unsigned short* Qhi = Vt + BTH;
  unsigned short* Qlo = Qhi + BTH;
  unsigned short* Khi = Qlo + BTH;
  unsigned short* Klo = Khi + BTH;
  float* out = (float*)d_out;

  wt_k<<<dim3(32, 4, 3), dim3(32, 8), 0, stream>>>(Wq, Wk, Wv, Whi, Wlo);
  qkv_k<<<3 * (B_ * T_ / 64), 256, 0, stream>>>(x, Whi, Wlo, Qhi, Qlo, Khi, Klo, Vt);
  flash_k<<<B_ * (T_ / 16), 256, 0, stream>>>(Qhi, Qlo, Khi, Klo, Vt, out);
}

// Round 6
// 371.028 us; speedup vs baseline: 1.4041x; 1.0638x over previous
//
#include <hip/hip_runtime.h>

#define B_ 4
#define T_ 4096
#define C_ 1024
#define H_ 128

typedef __attribute__((ext_vector_type(8))) __bf16 bf16x8;
typedef __attribute__((ext_vector_type(8))) unsigned short u16x8;
typedef __attribute__((ext_vector_type(4))) float f32x4;

__device__ __forceinline__ unsigned short f2bf(float f) {
  unsigned int u = __float_as_uint(f);
  return (unsigned short)((u + 0x7FFFu + ((u >> 16) & 1u)) >> 16);
}
__device__ __forceinline__ float bf2f(unsigned short h) {
  return __uint_as_float((unsigned)h << 16);
}
__device__ __forceinline__ bf16x8 ldb8(const unsigned short* p) {
  return *(const bf16x8*)(const void*)p;
}
// load 8 fp32, emit hi/lo bf16x8 fragments (hi+lo error ~2^-18 rel)
__device__ __forceinline__ void split8(const float* p, bf16x8& hi, bf16x8& lo) {
  float f[8];
  *(f32x4*)&f[0] = *(const f32x4*)(const void*)p;
  *(f32x4*)&f[4] = *(const f32x4*)(const void*)(p + 4);
  u16x8 h, l;
#pragma unroll
  for (int j = 0; j < 8; j++) {
    h[j] = f2bf(f[j]);
    l[j] = f2bf(f[j] - bf2f(h[j]));
  }
  hi = __builtin_bit_cast(bf16x8, h);
  lo = __builtin_bit_cast(bf16x8, l);
}

// ---------------------------------------------------------------------------
// Kernel 1: W [C][H] fp32 (x3) -> Wthi/Wtlo [.][H][C] bf16 (transpose + split)
// ---------------------------------------------------------------------------
__global__ void wt_k(const float* __restrict__ Wq, const float* __restrict__ Wk,
                     const float* __restrict__ Wv, unsigned short* __restrict__ Whi,
                     unsigned short* __restrict__ Wlo) {
  __shared__ float tile[32][33];
  int m = blockIdx.z;
  const float* W = (m == 0) ? Wq : ((m == 1) ? Wk : Wv);
  int c0 = blockIdx.x * 32, h0 = blockIdx.y * 32;
  int tx = threadIdx.x, ty = threadIdx.y;  // 32 x 8
#pragma unroll
  for (int i = 0; i < 4; i++)
    tile[ty + 8 * i][tx] = W[(size_t)(c0 + ty + 8 * i) * H_ + h0 + tx];
  __syncthreads();
  size_t base = (size_t)m * H_ * C_;
#pragma unroll
  for (int i = 0; i < 4; i++) {
    float f = tile[tx][ty + 8 * i];
    unsigned short hi = f2bf(f);
    size_t idx = base + (size_t)(h0 + ty + 8 * i) * C_ + c0 + tx;
    Whi[idx] = hi;
    if (m < 2) Wlo[idx] = f2bf(f - bf2f(hi));
  }
}

// ---------------------------------------------------------------------------
// Kernel 2: fused QKV projection, split-bf16 precision for Q,K.
// Writes Q,K PRE-SPLIT (Qhi/Qlo/Khi/Klo bf16 [B*T][H]); V transposed bf16.
// ---------------------------------------------------------------------------
#define WP 40  // LDS pitch: keeps ds_read_b128 at the free 2-way bank pattern
__global__ __launch_bounds__(256) void qkv_k(
    const float* __restrict__ x, const unsigned short* __restrict__ Whi,
    const unsigned short* __restrict__ Wlo, unsigned short* __restrict__ Qhi,
    unsigned short* __restrict__ Qlo, unsigned short* __restrict__ Khi,
    unsigned short* __restrict__ Klo, unsigned short* __restrict__ Vt) {
  int m = blockIdx.x % 3;
  int r0 = (blockIdx.x / 3) * 64;
  __shared__ unsigned short whi[128 * WP];
  __shared__ unsigned short wlo[128 * WP];
  int tid = threadIdx.x;
  int lane = tid & 63, wave = tid >> 6;
  int l15 = lane & 15, quad = lane >> 4;
  const unsigned short* Wmh = Whi + (size_t)m * H_ * C_;
  const unsigned short* Wml = Wlo + (size_t)m * H_ * C_;
  f32x4 acc[8];
#pragma unroll
  for (int n = 0; n < 8; n++) acc[n] = (f32x4){0.f, 0.f, 0.f, 0.f};
  int wrow = r0 + wave * 16 + l15;  // A-fragment row for this lane
  const float* xrow = x + (size_t)wrow * C_;

  for (int k0 = 0; k0 < C_; k0 += 32) {
    __syncthreads();
#pragma unroll
    for (int it = 0; it < 2; it++) {
      int c = it * 256 + tid;
      int h = c >> 2, kc = c & 3;
      *(int4*)(void*)(whi + h * WP + kc * 8) =
          *(const int4*)(const void*)(Wmh + (size_t)h * C_ + k0 + kc * 8);
      if (m < 2)
        *(int4*)(void*)(wlo + h * WP + kc * 8) =
            *(const int4*)(const void*)(Wml + (size_t)h * C_ + k0 + kc * 8);
    }
    __syncthreads();
    bf16x8 ahi, alo;
    split8(xrow + k0 + quad * 8, ahi, alo);
    if (m < 2) {
#pragma unroll
      for (int n = 0; n < 8; n++) {
        bf16x8 bhi = ldb8(whi + (n * 16 + l15) * WP + quad * 8);
        bf16x8 blo = ldb8(wlo + (n * 16 + l15) * WP + quad * 8);
        acc[n] = __builtin_amdgcn_mfma_f32_16x16x32_bf16(ahi, bhi, acc[n], 0, 0, 0);
        acc[n] = __builtin_amdgcn_mfma_f32_16x16x32_bf16(alo, bhi, acc[n], 0, 0, 0);
        acc[n] = __builtin_amdgcn_mfma_f32_16x16x32_bf16(ahi, blo, acc[n], 0, 0, 0);
      }
    } else {
#pragma unroll
      for (int n = 0; n < 8; n++) {
        bf16x8 bhi = ldb8(whi + (n * 16 + l15) * WP + quad * 8);
        acc[n] = __builtin_amdgcn_mfma_f32_16x16x32_bf16(ahi, bhi, acc[n], 0, 0, 0);
      }
    }
  }
  int ob = r0 + wave * 16 + quad * 4;
  if (m < 2) {
    unsigned short* Oh = (m == 0) ? Qhi : Khi;
    unsigned short* Ol = (m == 0) ? Qlo : Klo;
#pragma unroll
    for (int n = 0; n < 8; n++)
#pragma unroll
      for (int r = 0; r < 4; r++) {
        float f = acc[n][r];
        unsigned short hi = f2bf(f);
        size_t idx = (size_t)(ob + r) * H_ + n * 16 + l15;
        Oh[idx] = hi;
        Ol[idx] = f2bf(f - bf2f(hi));
      }
  } else {
#pragma unroll
    for (int n = 0; n < 8; n++)
#pragma unroll
      for (int r = 0; r < 4; r++) {
        int gr = ob + r;
        int bb = gr >> 12, t = gr & (T_ - 1);
        Vt[((size_t)bb * H_ + n * 16 + l15) * T_ + t] = f2bf(acc[n][r]);
      }
  }
}

// ---------------------------------------------------------------------------
// Kernel 3: flash attention, SPLIT-KV: 4 waves per block share one 16-row
// Q-tile; wave w handles kv-tiles kt = w, w+4, ...; LDS combine at the end.
// Register budget (the round-4/5 lesson): V-prefetch array (64 regs) +
// p[][] (16) pushed the live set to ~200 -> scratch spills at any cap.
// V now loads inline in the PV loop (TLP at 12 waves/CU hides L2 latency);
// exp() overwrites s in place. Live set ~135 < 170 cap at (256,3).
// ---------------------------------------------------------------------------
#define PP 72   // per-wave P-buffer pitch (u16): 2-way-free for b128 reads
#define OP 132  // combine buffer pitch (f32): quads land 2-way-free
__global__ __launch_bounds__(256, 3) void flash_k(
    const unsigned short* __restrict__ Qhi, const unsigned short* __restrict__ Qlo,
    const unsigned short* __restrict__ Khi, const unsigned short* __restrict__ Klo,
    const unsigned short* __restrict__ Vt, float* __restrict__ out) {
  __shared__ __align__(16) unsigned char smem[64 * OP * 4];  // 33792 B
  __shared__ float2 mlbuf[64];
  int tid = threadIdx.x;
  int wave = tid >> 6, lane = tid & 63;
  int l15 = lane & 15, quad = lane >> 4;
  unsigned short* pbuf = (unsigned short*)smem + wave * 16 * PP;  // wave-private
  float* obuf = (float*)(void*)smem;

  // XCD-affine mapping: batch = (blockIdx&7)>>1; longest q-tiles first (LPT)
  int g = blockIdx.x & 7;
  int j = blockIdx.x >> 3;  // 0..127
  int b = g >> 1;
  int i = 255 - (2 * j + (g & 1));
  int q0 = i * 16;
  size_t boff = (size_t)b * T_ * H_;
  const unsigned short* Khb = Khi + boff;
  const unsigned short* Klb = Klo + boff;
  const unsigned short* Vb = Vt + (size_t)b * H_ * T_;

  bf16x8 qh[4], ql[4];
  {
    const unsigned short* qrh = Qhi + boff + (size_t)(q0 + l15) * H_ + quad * 8;
    const unsigned short* qrl = Qlo + boff + (size_t)(q0 + l15) * H_ + quad * 8;
#pragma unroll
    for (int kk = 0; kk < 4; kk++) {
      qh[kk] = ldb8(qrh + kk * 32);
      ql[kk] = ldb8(qrl + kk * 32);
    }
  }
  f32x4 o[8];
#pragma unroll
  for (int n = 0; n < 8; n++) o[n] = (f32x4){0.f, 0.f, 0.f, 0.f};
  float mr[4] = {-1e30f, -1e30f, -1e30f, -1e30f};
  float lr[4] = {0.f, 0.f, 0.f, 0.f};

  int ktd = q0 >> 6;  // diagonal (masked) tile index
  for (int kt = wave; kt <= ktd; kt += 4) {
    f32x4 s[4];
#pragma unroll
    for (int n = 0; n < 4; n++) s[n] = (f32x4){0.f, 0.f, 0.f, 0.f};
#pragma unroll
    for (int n = 0; n < 4; n++) {
      size_t ro = (size_t)(kt * 64 + n * 16 + l15) * H_ + quad * 8;
      bf16x8 kh[4], kl[4];
#pragma unroll
      for (int kk = 0; kk < 4; kk++) {
        kh[kk] = ldb8(Khb + ro + kk * 32);
        kl[kk] = ldb8(Klb + ro + kk * 32);
      }
#pragma unroll
      for (int kk = 0; kk < 4; kk++) {
        s[n] = __builtin_amdgcn_mfma_f32_16x16x32_bf16(qh[kk], kh[kk], s[n], 0, 0, 0);
        s[n] = __builtin_amdgcn_mfma_f32_16x16x32_bf16(ql[kk], kh[kk], s[n], 0, 0, 0);
        s[n] = __builtin_amdgcn_mfma_f32_16x16x32_bf16(qh[kk], kl[kk], s[n], 0, 0, 0);
      }
    }
    if (kt == ktd) {  // causal mask on diagonal tile
#pragma unroll
      for (int n = 0; n < 4; n++) {
        int col = kt * 64 + n * 16 + l15;
#pragma unroll
        for (int r = 0; r < 4; r++) {
          int row = q0 + quad * 4 + r;
          if (col > row) s[n][r] = -1e30f;
        }
      }
    }
    float mnew[4];
#pragma unroll
    for (int r = 0; r < 4; r++)
      mnew[r] = fmaxf(fmaxf(s[0][r], s[1][r]), fmaxf(s[2][r], s[3][r]));
#pragma unroll
    for (int off = 1; off < 16; off <<= 1)
#pragma unroll
      for (int r = 0; r < 4; r++) mnew[r] = fmaxf(mnew[r], __shfl_xor(mnew[r], off));
    float alpha[4];
#pragma unroll
    for (int r = 0; r < 4; r++) {
      float mi = fmaxf(mr[r], mnew[r]);
      alpha[r] = __expf(mr[r] - mi);
      mr[r] = mi;
    }
    // exp in place: s becomes P (saves 16 registers vs separate p[][])
    float rs[4];
#pragma unroll
    for (int n = 0; n < 4; n++)
#pragma unroll
      for (int r = 0; r < 4; r++) s[n][r] = __expf(s[n][r] - mr[r]);
#pragma unroll
    for (int r = 0; r < 4; r++) rs[r] = (s[0][r] + s[1][r]) + (s[2][r] + s[3][r]);
#pragma unroll
    for (int off = 1; off < 16; off <<= 1)
#pragma unroll
      for (int r = 0; r < 4; r++) rs[r] += __shfl_xor(rs[r], off);
#pragma unroll
    for (int r = 0; r < 4; r++) lr[r] = lr[r] * alpha[r] + rs[r];
#pragma unroll
    for (int n = 0; n < 8; n++)
#pragma unroll
      for (int r = 0; r < 4; r++) o[n][r] *= alpha[r];
    // P: C-layout -> A-layout via wave-private LDS (lgkm ordering suffices)
    asm volatile("s_waitcnt lgkmcnt(0)" ::: "memory");
#pragma unroll
    for (int n = 0; n < 4; n++)
#pragma unroll
      for (int r = 0; r < 4; r++)
        pbuf[(quad * 4 + r) * PP + n * 16 + l15] = f2bf(s[n][r]);
    asm volatile("s_waitcnt lgkmcnt(0)" ::: "memory");
    // O += P @ V : V fragments load inline (no prefetch array — reg budget)
#pragma unroll
    for (int ks = 0; ks < 2; ks++) {
      bf16x8 pa = ldb8(pbuf + l15 * PP + ks * 32 + quad * 8);
#pragma unroll
      for (int n = 0; n < 8; n++) {
        bf16x8 vf = ldb8(Vb + (size_t)(n * 16 + l15) * T_ + kt * 64 + ks * 32 + quad * 8);
        o[n] = __builtin_amdgcn_mfma_f32_16x16x32_bf16(pa, vf, o[n], 0, 0, 0);
      }
    }
  }

  // ---- cross-wave combine ----
  if (l15 == 0) {
#pragma unroll
    for (int r = 0; r < 4; r++)
      mlbuf[wave * 16 + quad * 4 + r] = make_float2(mr[r], lr[r]);
  }
  __syncthreads();
  // scale own partial by exp(m_w - M) and stage to obuf
  float f[4];
#pragma unroll
  for (int r = 0; r < 4; r++) {
    int row = quad * 4 + r;
    float M = mlbuf[row].x;
#pragma unroll
    for (int w2 = 1; w2 < 4; w2++) M = fmaxf(M, mlbuf[w2 * 16 + row].x);
    f[r] = __expf(mr[r] - M);
  }
#pragma unroll
  for (int n = 0; n < 8; n++)
#pragma unroll
    for (int r = 0; r < 4; r++)
      obuf[(size_t)(wave * 16 + quad * 4 + r) * OP + n * 16 + l15] = o[n][r] * f[r];
  __syncthreads();
  // sum 4 partials; wave w owns rows w*4..w*4+3
  int row = wave * 4 + quad;
  int c0 = l15 * 8;
  float M = mlbuf[row].x;
#pragma unroll
  for (int w2 = 1; w2 < 4; w2++) M = fmaxf(M, mlbuf[w2 * 16 + row].x);
  float L = 0.f;
#pragma unroll
  for (int w2 = 0; w2 < 4; w2++)
    L += __expf(mlbuf[w2 * 16 + row].x - M) * mlbuf[w2 * 16 + row].y;
  f32x4 a0 = (f32x4){0.f, 0.f, 0.f, 0.f}, a1 = a0;
#pragma unroll
  for (int w2 = 0; w2 < 4; w2++) {
    const float* src = obuf + (size_t)(w2 * 16 + row) * OP + c0;
    a0 += *(const f32x4*)(const void*)src;
    a1 += *(const f32x4*)(const void*)(src + 4);
  }
  float invL = 1.0f / L;
  float* op = out + ((size_t)b * T_ + q0 + row) * H_ + c0;
  *(f32x4*)(void*)op = a0 * invL;
  *(f32x4*)(void*)(op + 4) = a1 * invL;
}

// ---------------------------------------------------------------------------
extern "C" void kernel_launch(void* const* d_in, const int* in_sizes, int n_in,
                              void* d_out, int out_size, void* d_ws, size_t ws_size,
                              hipStream_t stream) {
  const float* x  = (const float*)d_in[0];
  const float* Wq = (const float*)d_in[1];
  const float* Wk = (const float*)d_in[2];
  const float* Wv = (const float*)d_in[3];
  const size_t BTH = (size_t)B_ * T_ * H_;
  unsigned short* Whi = (unsigned short*)d_ws;   // 3*H*C
  unsigned short* Wlo = Whi + 3 * H_ * C_;       // 2*H*C (Q,K only)
  unsigned short* Vt  = Wlo + 2 * H_ * C_;       // BTH
  unsigned short* Qhi = Vt + BTH;
  unsigned short* Qlo = Qhi + BTH;
  unsigned short* Khi = Qlo + BTH;
  unsigned short* Klo = Khi + BTH;
  float* out = (float*)d_out;

  wt_k<<<dim3(32, 4, 3), dim3(32, 8), 0, stream>>>(Wq, Wk, Wv, Whi, Wlo);
  qkv_k<<<3 * (B_ * T_ / 64), 256, 0, stream>>>(x, Whi, Wlo, Qhi, Qlo, Khi, Klo, Vt);
  flash_k<<<B_ * (T_ / 16), 256, 0, stream>>>(Qhi, Qlo, Khi, Klo, Vt, out);
}

// Round 7
// 306.329 us; speedup vs baseline: 1.7006x; 1.2112x over previous
//
#include <hip/hip_runtime.h>

#define B_ 4
#define T_ 4096
#define C_ 1024
#define H_ 128

typedef __attribute__((ext_vector_type(8))) __bf16 bf16x8;
typedef __attribute__((ext_vector_type(8))) unsigned short u16x8;
typedef __attribute__((ext_vector_type(4))) float f32x4;

__device__ __forceinline__ unsigned short f2bf(float f) {
  unsigned int u = __float_as_uint(f);
  return (unsigned short)((u + 0x7FFFu + ((u >> 16) & 1u)) >> 16);
}
__device__ __forceinline__ float bf2f(unsigned short h) {
  return __uint_as_float((unsigned)h << 16);
}
__device__ __forceinline__ bf16x8 ldb8(const unsigned short* p) {
  return *(const bf16x8*)(const void*)p;
}
// async global->LDS DMA, 16B per lane; LDS dest = uniform base + lane*16
__device__ __forceinline__ void async16(unsigned short* lds, const unsigned short* g) {
  __builtin_amdgcn_global_load_lds(
      (const __attribute__((address_space(1))) unsigned int*)(const void*)g,
      (__attribute__((address_space(3))) unsigned int*)(void*)lds, 16, 0, 0);
}
// load 8 fp32, emit hi/lo bf16x8 fragments (hi+lo error ~2^-18 rel)
__device__ __forceinline__ void split8(const float* p, bf16x8& hi, bf16x8& lo) {
  float f[8];
  *(f32x4*)&f[0] = *(const f32x4*)(const void*)p;
  *(f32x4*)&f[4] = *(const f32x4*)(const void*)(p + 4);
  u16x8 h, l;
#pragma unroll
  for (int j = 0; j < 8; j++) {
    h[j] = f2bf(f[j]);
    l[j] = f2bf(f[j] - bf2f(h[j]));
  }
  hi = __builtin_bit_cast(bf16x8, h);
  lo = __builtin_bit_cast(bf16x8, l);
}

// Swizzled layouts (so flat global_load_lds staging is LDS-bank-conflict-free):
// K[t][h]: 16B chunk c=h>>3 stored at chunk position (c + t) & 15 within row t.
// Vt[h][t]: within each 64-wide t-tile, chunk tc=(t>>3)&7 stored at (tc + h) & 7.

// ---------------------------------------------------------------------------
// Kernel 1: W [C][H] fp32 (x3) -> Wthi/Wtlo [.][H][C] bf16 (transpose + split)
// ---------------------------------------------------------------------------
__global__ void wt_k(const float* __restrict__ Wq, const float* __restrict__ Wk,
                     const float* __restrict__ Wv, unsigned short* __restrict__ Whi,
                     unsigned short* __restrict__ Wlo) {
  __shared__ float tile[32][33];
  int m = blockIdx.z;
  const float* W = (m == 0) ? Wq : ((m == 1) ? Wk : Wv);
  int c0 = blockIdx.x * 32, h0 = blockIdx.y * 32;
  int tx = threadIdx.x, ty = threadIdx.y;  // 32 x 8
#pragma unroll
  for (int i = 0; i < 4; i++)
    tile[ty + 8 * i][tx] = W[(size_t)(c0 + ty + 8 * i) * H_ + h0 + tx];
  __syncthreads();
  size_t base = (size_t)m * H_ * C_;
#pragma unroll
  for (int i = 0; i < 4; i++) {
    float f = tile[tx][ty + 8 * i];
    unsigned short hi = f2bf(f);
    size_t idx = base + (size_t)(h0 + ty + 8 * i) * C_ + c0 + tx;
    Whi[idx] = hi;
    if (m < 2) Wlo[idx] = f2bf(f - bf2f(hi));
  }
}

// ---------------------------------------------------------------------------
// Kernel 2: fused QKV projection. Q linear hi/lo; K swizzled hi/lo;
// V transposed + swizzled (layouts above).
// ---------------------------------------------------------------------------
#define WP 40
__global__ __launch_bounds__(256) void qkv_k(
    const float* __restrict__ x, const unsigned short* __restrict__ Whi,
    const unsigned short* __restrict__ Wlo, unsigned short* __restrict__ Qhi,
    unsigned short* __restrict__ Qlo, unsigned short* __restrict__ Khi,
    unsigned short* __restrict__ Klo, unsigned short* __restrict__ Vt) {
  int m = blockIdx.x % 3;
  int r0 = (blockIdx.x / 3) * 64;
  __shared__ unsigned short whi[128 * WP];
  __shared__ unsigned short wlo[128 * WP];
  int tid = threadIdx.x;
  int lane = tid & 63, wave = tid >> 6;
  int l15 = lane & 15, quad = lane >> 4;
  const unsigned short* Wmh = Whi + (size_t)m * H_ * C_;
  const unsigned short* Wml = Wlo + (size_t)m * H_ * C_;
  f32x4 acc[8];
#pragma unroll
  for (int n = 0; n < 8; n++) acc[n] = (f32x4){0.f, 0.f, 0.f, 0.f};
  int wrow = r0 + wave * 16 + l15;
  const float* xrow = x + (size_t)wrow * C_;

  for (int k0 = 0; k0 < C_; k0 += 32) {
    __syncthreads();
#pragma unroll
    for (int it = 0; it < 2; it++) {
      int c = it * 256 + tid;
      int h = c >> 2, kc = c & 3;
      *(int4*)(void*)(whi + h * WP + kc * 8) =
          *(const int4*)(const void*)(Wmh + (size_t)h * C_ + k0 + kc * 8);
      if (m < 2)
        *(int4*)(void*)(wlo + h * WP + kc * 8) =
            *(const int4*)(const void*)(Wml + (size_t)h * C_ + k0 + kc * 8);
    }
    __syncthreads();
    bf16x8 ahi, alo;
    split8(xrow + k0 + quad * 8, ahi, alo);
    if (m < 2) {
#pragma unroll
      for (int n = 0; n < 8; n++) {
        bf16x8 bhi = ldb8(whi + (n * 16 + l15) * WP + quad * 8);
        bf16x8 blo = ldb8(wlo + (n * 16 + l15) * WP + quad * 8);
        acc[n] = __builtin_amdgcn_mfma_f32_16x16x32_bf16(ahi, bhi, acc[n], 0, 0, 0);
        acc[n] = __builtin_amdgcn_mfma_f32_16x16x32_bf16(alo, bhi, acc[n], 0, 0, 0);
        acc[n] = __builtin_amdgcn_mfma_f32_16x16x32_bf16(ahi, blo, acc[n], 0, 0, 0);
      }
    } else {
#pragma unroll
      for (int n = 0; n < 8; n++) {
        bf16x8 bhi = ldb8(whi + (n * 16 + l15) * WP + quad * 8);
        acc[n] = __builtin_amdgcn_mfma_f32_16x16x32_bf16(ahi, bhi, acc[n], 0, 0, 0);
      }
    }
  }
  int ob = r0 + wave * 16 + quad * 4;
  if (m == 0) {  // Q: linear
#pragma unroll
    for (int n = 0; n < 8; n++)
#pragma unroll
      for (int r = 0; r < 4; r++) {
        float f = acc[n][r];
        unsigned short hi = f2bf(f);
        size_t idx = (size_t)(ob + r) * H_ + n * 16 + l15;
        Qhi[idx] = hi;
        Qlo[idx] = f2bf(f - bf2f(hi));
      }
  } else if (m == 1) {  // K: chunk-rotated by t
#pragma unroll
    for (int n = 0; n < 8; n++)
#pragma unroll
      for (int r = 0; r < 4; r++) {
        int t = ob + r;
        int h = n * 16 + l15;
        int hs = (((t + (h >> 3)) & 15) << 3) | (h & 7);
        float f = acc[n][r];
        unsigned short hi = f2bf(f);
        size_t idx = (size_t)t * H_ + hs;
        Khi[idx] = hi;
        Klo[idx] = f2bf(f - bf2f(hi));
      }
  } else {  // V: transposed, chunk-rotated by h within 64-wide t tiles
#pragma unroll
    for (int n = 0; n < 8; n++)
#pragma unroll
      for (int r = 0; r < 4; r++) {
        int gr = ob + r;
        int bb = gr >> 12, t = gr & (T_ - 1);
        int h = n * 16 + l15;
        int ts = (t & ~63) | ((((t >> 3) + h) & 7) << 3) | (t & 7);
        Vt[((size_t)bb * H_ + h) * T_ + ts] = f2bf(acc[n][r]);
      }
  }
}

// ---------------------------------------------------------------------------
// Kernel 3: flash attention. Block = 128 thr (2 waves) = 32 Q rows; both
// waves iterate the SAME kt; K(hi+lo) and V tiles DMA'd to LDS once per
// block-iter via global_load_lds (contiguous 1KB/instr — round 6 showed the
// per-wave 16-row-scatter global fragment loads were the serializer).
// P-transpose buffer overlays the dead K region. No cross-wave combine.
// ---------------------------------------------------------------------------
__global__ __launch_bounds__(128, 2) void flash_k(
    const unsigned short* __restrict__ Qhi, const unsigned short* __restrict__ Qlo,
    const unsigned short* __restrict__ Khi, const unsigned short* __restrict__ Klo,
    const unsigned short* __restrict__ Vt, float* __restrict__ out) {
  __shared__ __align__(16) unsigned short sK[2 * 64 * 128];  // hi | lo, 32 KB
  __shared__ __align__(16) unsigned short sV[128 * 64];      // 16 KB
  int tid = threadIdx.x;
  int wave = tid >> 6, lane = tid & 63;
  int l15 = lane & 15, quad = lane >> 4;

  // 512 blocks; k and k+256 are complementary-length (sum ~65 kt-iters) so
  // breadth-first dispatch pairs long+short on each CU. batch = k&3 spreads
  // each batch over 2 XCDs' worth of blocks for K/V L2 locality.
  int k = blockIdx.x;
  int k2 = k & 255;
  int b = k2 & 3;
  int j = (k >> 8) ? (k2 >> 2) : (127 - (k2 >> 2));  // 32-row tile idx 0..127
  int q0 = j * 32;
  int q0w = q0 + wave * 16;
  size_t boff = (size_t)b * T_ * H_;
  const unsigned short* Khb = Khi + boff;
  const unsigned short* Klb = Klo + boff;
  const unsigned short* Vb = Vt + (size_t)b * H_ * T_;
  unsigned short* pbuf = sK + wave * 16 * 72;  // overlays Khi region

  bf16x8 qh[4], ql[4];
  {
    const unsigned short* qrh = Qhi + boff + (size_t)(q0w + l15) * H_ + quad * 8;
    const unsigned short* qrl = Qlo + boff + (size_t)(q0w + l15) * H_ + quad * 8;
#pragma unroll
    for (int kk = 0; kk < 4; kk++) {
      qh[kk] = ldb8(qrh + kk * 32);
      ql[kk] = ldb8(qrl + kk * 32);
    }
  }
  f32x4 o[8];
#pragma unroll
  for (int n = 0; n < 8; n++) o[n] = (f32x4){0.f, 0.f, 0.f, 0.f};
  float mr[4] = {-1e30f, -1e30f, -1e30f, -1e30f};
  float lr[4] = {0.f, 0.f, 0.f, 0.f};

  int ktd = q0 >> 6;  // diagonal tile
  for (int kt = 0; kt <= ktd; kt++) {
    __syncthreads();  // prior iter's K/V/P reads complete
    // ---- stage: wave 0 -> Khi + V[0:64), wave 1 -> Klo + V[64:128) ----
    {
      const unsigned short* kg = wave ? Klb : Khb;
      unsigned short* kd = wave ? (sK + 64 * 128) : sK;
#pragma unroll
      for (int i2 = 0; i2 < 16; i2++)
        async16(kd + i2 * 512,
                kg + (size_t)(kt * 64 + i2 * 4 + (lane >> 4)) * H_ + (lane & 15) * 8);
#pragma unroll
      for (int i2 = 0; i2 < 8; i2++) {
        int iv = wave * 8 + i2;
        async16(sV + iv * 512,
                Vb + (size_t)(iv * 8 + (lane >> 3)) * T_ + kt * 64 + (lane & 7) * 8);
      }
    }
    __syncthreads();  // staging visible (barrier drains vmcnt)
    // ---- S = Q K^T from LDS (swizzle-aware, conflict-free) ----
    f32x4 s[4];
#pragma unroll
    for (int n = 0; n < 4; n++) {
      int lr2 = n * 16 + l15;
      bf16x8 kh[4], kl[4];
#pragma unroll
      for (int kk = 0; kk < 4; kk++) {
        int p = (l15 + kk * 4 + quad) & 15;
        kh[kk] = ldb8(sK + lr2 * 128 + p * 8);
        kl[kk] = ldb8(sK + 64 * 128 + lr2 * 128 + p * 8);
      }
      f32x4 sa = (f32x4){0.f, 0.f, 0.f, 0.f};
      f32x4 sb = (f32x4){0.f, 0.f, 0.f, 0.f};
#pragma unroll
      for (int kk = 0; kk < 4; kk++)
        sa = __builtin_amdgcn_mfma_f32_16x16x32_bf16(qh[kk], kh[kk], sa, 0, 0, 0);
#pragma unroll
      for (int kk = 0; kk < 4; kk++) {
        sb = __builtin_amdgcn_mfma_f32_16x16x32_bf16(ql[kk], kh[kk], sb, 0, 0, 0);
        sb = __builtin_amdgcn_mfma_f32_16x16x32_bf16(qh[kk], kl[kk], sb, 0, 0, 0);
      }
      s[n] = sa + sb;
    }
    if (kt == ktd) {  // causal mask on diagonal tile
#pragma unroll
      for (int n = 0; n < 4; n++) {
        int col = kt * 64 + n * 16 + l15;
#pragma unroll
        for (int r = 0; r < 4; r++)
          if (col > q0w + quad * 4 + r) s[n][r] = -1e30f;
      }
    }
    // ---- online softmax (rows on (quad,r); reduce over 16 l15 lanes) ----
    float mnew[4];
#pragma unroll
    for (int r = 0; r < 4; r++)
      mnew[r] = fmaxf(fmaxf(s[0][r], s[1][r]), fmaxf(s[2][r], s[3][r]));
#pragma unroll
    for (int off = 1; off < 16; off <<= 1)
#pragma unroll
      for (int r = 0; r < 4; r++) mnew[r] = fmaxf(mnew[r], __shfl_xor(mnew[r], off));
    float alpha[4];
#pragma unroll
    for (int r = 0; r < 4; r++) {
      float mi = fmaxf(mr[r], mnew[r]);
      alpha[r] = __expf(mr[r] - mi);
      mr[r] = mi;
    }
    float rs[4];
#pragma unroll
    for (int n = 0; n < 4; n++)
#pragma unroll
      for (int r = 0; r < 4; r++) s[n][r] = __expf(s[n][r] - mr[r]);
#pragma unroll
    for (int r = 0; r < 4; r++) rs[r] = (s[0][r] + s[1][r]) + (s[2][r] + s[3][r]);
#pragma unroll
    for (int off = 1; off < 16; off <<= 1)
#pragma unroll
      for (int r = 0; r < 4; r++) rs[r] += __shfl_xor(rs[r], off);
#pragma unroll
    for (int r = 0; r < 4; r++) lr[r] = lr[r] * alpha[r] + rs[r];
#pragma unroll
    for (int n = 0; n < 8; n++)
#pragma unroll
      for (int r = 0; r < 4; r++) o[n][r] *= alpha[r];
    // ---- P: C-layout -> A-layout via LDS slot overlaying dead K region ----
    __syncthreads();  // all waves done reading K before overlay
#pragma unroll
    for (int n = 0; n < 4; n++)
#pragma unroll
      for (int r = 0; r < 4; r++)
        pbuf[(quad * 4 + r) * 72 + n * 16 + l15] = f2bf(s[n][r]);
    asm volatile("s_waitcnt lgkmcnt(0)" ::: "memory");  // own writes visible
    // ---- O += P @ V from LDS ----
#pragma unroll
    for (int ks = 0; ks < 2; ks++) {
      bf16x8 pa = ldb8(pbuf + l15 * 72 + ks * 32 + quad * 8);
#pragma unroll
      for (int n = 0; n < 8; n++) {
        int h = n * 16 + l15;
        int tcp = (ks * 4 + quad + l15) & 7;
        bf16x8 vf = ldb8(sV + h * 64 + tcp * 8);
        o[n] = __builtin_amdgcn_mfma_f32_16x16x32_bf16(pa, vf, o[n], 0, 0, 0);
      }
    }
  }
  float inv[4];
#pragma unroll
  for (int r = 0; r < 4; r++) inv[r] = 1.0f / lr[r];
  float* orow = out + ((size_t)b * T_ + q0w + quad * 4) * H_;
#pragma unroll
  for (int n = 0; n < 8; n++)
#pragma unroll
    for (int r = 0; r < 4; r++)
      orow[(size_t)r * H_ + n * 16 + l15] = o[n][r] * inv[r];
}

// ---------------------------------------------------------------------------
extern "C" void kernel_launch(void* const* d_in, const int* in_sizes, int n_in,
                              void* d_out, int out_size, void* d_ws, size_t ws_size,
                              hipStream_t stream) {
  const float* x  = (const float*)d_in[0];
  const float* Wq = (const float*)d_in[1];
  const float* Wk = (const float*)d_in[2];
  const float* Wv = (const float*)d_in[3];
  const size_t BTH = (size_t)B_ * T_ * H_;
  unsigned short* Whi = (unsigned short*)d_ws;   // 3*H*C
  unsigned short* Wlo = Whi + 3 * H_ * C_;       // 2*H*C (Q,K only)
  unsigned short* Vt  = Wlo + 2 * H_ * C_;       // BTH
  unsigned short* Qhi = Vt + BTH;
  unsigned short* Qlo = Qhi + BTH;
  unsigned short* Khi = Qlo + BTH;
  unsigned short* Klo = Khi + BTH;
  float* out = (float*)d_out;

  wt_k<<<dim3(32, 4, 3), dim3(32, 8), 0, stream>>>(Wq, Wk, Wv, Whi, Wlo);
  qkv_k<<<3 * (B_ * T_ / 64), 256, 0, stream>>>(x, Whi, Wlo, Qhi, Qlo, Khi, Klo, Vt);
  flash_k<<<512, 128, 0, stream>>>(Qhi, Qlo, Khi, Klo, Vt, out);
}

// Round 8
// 284.721 us; speedup vs baseline: 1.8297x; 1.0759x over previous
//
#include <hip/hip_runtime.h>

#define B_ 4
#define T_ 4096
#define C_ 1024
#define H_ 128

typedef __attribute__((ext_vector_type(8))) __bf16 bf16x8;
typedef __attribute__((ext_vector_type(8))) unsigned short u16x8;
typedef __attribute__((ext_vector_type(4))) float f32x4;

__device__ __forceinline__ unsigned short f2bf(float f) {
  unsigned int u = __float_as_uint(f);
  return (unsigned short)((u + 0x7FFFu + ((u >> 16) & 1u)) >> 16);
}
__device__ __forceinline__ float bf2f(unsigned short h) {
  return __uint_as_float((unsigned)h << 16);
}
__device__ __forceinline__ bf16x8 ldb8(const unsigned short* p) {
  return *(const bf16x8*)(const void*)p;
}
// async global->LDS DMA: 16B/lane, LDS dest = wave-uniform base + lane*16
__device__ __forceinline__ void async16(void* lds, const void* g) {
  __builtin_amdgcn_global_load_lds(
      (const __attribute__((address_space(1))) unsigned int*)g,
      (__attribute__((address_space(3))) unsigned int*)lds, 16, 0, 0);
}
__device__ __forceinline__ void split8a(const float* f, bf16x8& hi, bf16x8& lo) {
  u16x8 h, l;
#pragma unroll
  for (int j = 0; j < 8; j++) {
    h[j] = f2bf(f[j]);
    l[j] = f2bf(f[j] - bf2f(h[j]));
  }
  hi = __builtin_bit_cast(bf16x8, h);
  lo = __builtin_bit_cast(bf16x8, l);
}

// Fragment-ordered K/V global layouts (per batch, elem offsets):
//   K(t,h): kt=t>>6 n=(t>>4)&3 lk=t&15 kk=h>>5 qk=(h>>3)&3 e=h&7
//           off = ((kt*16+n*4+kk)*64 + qk*16+lk)*8 + e
//   V(t,h): kt=t>>6 ks=(t>>5)&1 qv=(t>>3)&3 j=t&7 nv=h>>4 lv=h&15
//           off = ((kt*16+ks*8+nv)*64 + qv*16+lv)*8 + j
// => flash fragment load for (kt,n,kk)/(kt,ks,n) is base + lane*16B: one
//    coalesced 1KB transaction per wave (R6's 16-row scatter eliminated).

// ---------------------------------------------------------------------------
// Kernel 1: W [C][H] fp32 -> Wthi/Wtlo [.][H][C] bf16, transpose + split,
// with 16B chunks rotated by (h&7) inside each 64-elem k-window so qkv's
// flat global_load_lds staging lands LDS-bank-uniform.
// ---------------------------------------------------------------------------
__global__ void wt_k(const float* __restrict__ Wq, const float* __restrict__ Wk,
                     const float* __restrict__ Wv, unsigned short* __restrict__ Whi,
                     unsigned short* __restrict__ Wlo) {
  __shared__ float tile[32][33];
  int m = blockIdx.z;
  const float* W = (m == 0) ? Wq : ((m == 1) ? Wk : Wv);
  int c0 = blockIdx.x * 32, h0 = blockIdx.y * 32;
  int tx = threadIdx.x, ty = threadIdx.y;  // 32 x 8
#pragma unroll
  for (int i = 0; i < 4; i++)
    tile[ty + 8 * i][tx] = W[(size_t)(c0 + ty + 8 * i) * H_ + h0 + tx];
  __syncthreads();
  size_t base = (size_t)m * H_ * C_;
#pragma unroll
  for (int i = 0; i < 4; i++) {
    float f = tile[tx][ty + 8 * i];
    unsigned short hi = f2bf(f);
    int h = h0 + ty + 8 * i;
    int kg = c0 + tx;
    int w0 = kg >> 6, c = (kg >> 3) & 7, e = kg & 7;
    size_t idx = base + (size_t)h * C_ + w0 * 64 + ((c + (h & 7)) & 7) * 8 + e;
    Whi[idx] = hi;
    if (m < 2) Wlo[idx] = f2bf(f - bf2f(hi));
  }
}

// ---------------------------------------------------------------------------
// Kernel 2: fused QKV projection, BK=64. x and W tiles staged via
// global_load_lds DMA (x's swizzle folded into the gather addresses — the
// old per-lane x reads were a 16-row scatter, same disease as R6 flash).
// Q written linear hi/lo; K written fragment-order hi/lo; V fragment-order.
// ---------------------------------------------------------------------------
__global__ __launch_bounds__(256, 3) void qkv_k(
    const float* __restrict__ x, const unsigned short* __restrict__ Whi,
    const unsigned short* __restrict__ Wlo, unsigned short* __restrict__ Qhi,
    unsigned short* __restrict__ Qlo, unsigned short* __restrict__ Khf,
    unsigned short* __restrict__ Klf, unsigned short* __restrict__ Vf) {
  int m = blockIdx.x % 3;
  int r0 = (blockIdx.x / 3) * 64;
  __shared__ __align__(16) float sx[64 * 64];            // 16 KB, row=256B swizzled
  __shared__ __align__(16) unsigned short swh[128 * 64]; // 16 KB, row=128B swizzled
  __shared__ __align__(16) unsigned short swl[128 * 64]; // 16 KB
  int tid = threadIdx.x;
  int lane = tid & 63, wave = tid >> 6;
  int l15 = lane & 15, quad = lane >> 4;
  const unsigned short* Wmh = Whi + (size_t)m * H_ * C_;
  const unsigned short* Wml = Wlo + (size_t)m * H_ * C_;
  f32x4 acc[8];
#pragma unroll
  for (int n = 0; n < 8; n++) acc[n] = (f32x4){0.f, 0.f, 0.f, 0.f};

  for (int k0 = 0; k0 < C_; k0 += 64) {
    __syncthreads();  // prior iter's LDS reads done
#pragma unroll
    for (int i = 0; i < 4; i++) {
      int s = (wave * 4 + i) * 64 + lane;
      {  // x: LDS slot (tr,p) <- x[r0+tr][k0 + ((p-tr)&15)*4]  (rotated gather)
        int tr = s >> 4, p = s & 15;
        async16((unsigned short*)sx + (size_t)(wave * 4 + i) * 512,
                x + (size_t)(r0 + tr) * C_ + k0 + ((p - tr) & 15) * 4);
      }
      {  // W: flat copy (global already rotated by wt_k)
        int hr = s >> 3, p = s & 7;
        async16(swh + (size_t)(wave * 4 + i) * 512,
                Wmh + (size_t)hr * C_ + k0 + p * 8);
        if (m < 2)
          async16(swl + (size_t)(wave * 4 + i) * 512,
                  Wml + (size_t)hr * C_ + k0 + p * 8);
      }
    }
    __syncthreads();  // barrier drains vmcnt -> staging visible
#pragma unroll
    for (int kk = 0; kk < 2; kk++) {
      float xa[8];
#pragma unroll
      for (int half = 0; half < 2; half++) {
        int p = (kk * 8 + quad * 2 + half + l15) & 15;
        *(f32x4*)&xa[half * 4] =
            *(const f32x4*)(const void*)(sx + (wave * 16 + l15) * 64 + p * 4);
      }
      bf16x8 ahi, alo;
      split8a(xa, ahi, alo);
      if (m < 2) {
#pragma unroll
        for (int n = 0; n < 8; n++) {
          int p = (kk * 4 + quad + l15) & 7;
          bf16x8 bhi = ldb8(swh + (n * 16 + l15) * 64 + p * 8);
          bf16x8 blo = ldb8(swl + (n * 16 + l15) * 64 + p * 8);
          acc[n] = __builtin_amdgcn_mfma_f32_16x16x32_bf16(ahi, bhi, acc[n], 0, 0, 0);
          acc[n] = __builtin_amdgcn_mfma_f32_16x16x32_bf16(alo, bhi, acc[n], 0, 0, 0);
          acc[n] = __builtin_amdgcn_mfma_f32_16x16x32_bf16(ahi, blo, acc[n], 0, 0, 0);
        }
      } else {
#pragma unroll
        for (int n = 0; n < 8; n++) {
          int p = (kk * 4 + quad + l15) & 7;
          bf16x8 bhi = ldb8(swh + (n * 16 + l15) * 64 + p * 8);
          acc[n] = __builtin_amdgcn_mfma_f32_16x16x32_bf16(ahi, bhi, acc[n], 0, 0, 0);
        }
      }
    }
  }
  // epilogue: C-layout row = quad*4+r, col = n8*16+l15
  int ob = r0 + wave * 16 + quad * 4;
  if (m == 0) {  // Q: linear hi/lo
#pragma unroll
    for (int n8 = 0; n8 < 8; n8++)
#pragma unroll
      for (int r = 0; r < 4; r++) {
        float f = acc[n8][r];
        unsigned short hi = f2bf(f);
        size_t idx = (size_t)(ob + r) * H_ + n8 * 16 + l15;
        Qhi[idx] = hi;
        Qlo[idx] = f2bf(f - bf2f(hi));
      }
  } else if (m == 1) {  // K: fragment order hi/lo
#pragma unroll
    for (int n8 = 0; n8 < 8; n8++)
#pragma unroll
      for (int r = 0; r < 4; r++) {
        int gr = ob + r;
        int bb = gr >> 12, t = gr & (T_ - 1);
        int kt = t >> 6, tr = t & 63, nf = tr >> 4, lk = tr & 15;
        int h = n8 * 16 + l15;
        int kkf = h >> 5, qk = (h >> 3) & 3, e = h & 7;
        size_t idx = (size_t)bb * T_ * H_ +
                     (size_t)((kt * 16 + nf * 4 + kkf) * 64 + qk * 16 + lk) * 8 + e;
        float f = acc[n8][r];
        unsigned short hi = f2bf(f);
        Khf[idx] = hi;
        Klf[idx] = f2bf(f - bf2f(hi));
      }
  } else {  // V: fragment order
#pragma unroll
    for (int n8 = 0; n8 < 8; n8++)
#pragma unroll
      for (int r = 0; r < 4; r++) {
        int gr = ob + r;
        int bb = gr >> 12, t = gr & (T_ - 1);
        int kt = t >> 6, ks = (t >> 5) & 1, qv = (t >> 3) & 3, jj = t & 7;
        size_t idx = (size_t)bb * T_ * H_ +
                     (size_t)((kt * 16 + ks * 8 + n8) * 64 + qv * 16 + l15) * 8 + jj;
        Vf[idx] = f2bf(acc[n8][r]);
      }
  }
}

// ---------------------------------------------------------------------------
// Kernel 3: flash attention, in-block split-KV (4 waves, one 16-row Q-tile,
// wave w: kt = w, w+4, ...). K/V fragment loads from global are now
// base+lane*16 coalesced 1KB transactions (no staging, no barriers in loop).
// Loop body = round 6's proven no-spill shape (VGPR 76).
// ---------------------------------------------------------------------------
#define PP 72   // per-wave P-buffer pitch (u16)
#define OP 132  // combine buffer pitch (f32)
__global__ __launch_bounds__(256, 3) void flash_k(
    const unsigned short* __restrict__ Qhi, const unsigned short* __restrict__ Qlo,
    const unsigned short* __restrict__ Khf, const unsigned short* __restrict__ Klf,
    const unsigned short* __restrict__ Vf, float* __restrict__ out) {
  __shared__ __align__(16) unsigned char smem[64 * OP * 4];  // 33792 B
  __shared__ float2 mlbuf[64];
  int tid = threadIdx.x;
  int wave = tid >> 6, lane = tid & 63;
  int l15 = lane & 15, quad = lane >> 4;
  unsigned short* pbuf = (unsigned short*)smem + wave * 16 * PP;  // wave-private
  float* obuf = (float*)(void*)smem;

  int g = blockIdx.x & 7;
  int j = blockIdx.x >> 3;
  int b = g >> 1;
  int i = 255 - (2 * j + (g & 1));  // longest q-tiles first
  int q0 = i * 16;
  size_t boff = (size_t)b * T_ * H_;
  const unsigned short* Khb = Khf + boff;
  const unsigned short* Klb = Klf + boff;
  const unsigned short* Vb = Vf + boff;

  bf16x8 qh[4], ql[4];
  {
    const unsigned short* qrh = Qhi + boff + (size_t)(q0 + l15) * H_ + quad * 8;
    const unsigned short* qrl = Qlo + boff + (size_t)(q0 + l15) * H_ + quad * 8;
#pragma unroll
    for (int kk = 0; kk < 4; kk++) {
      qh[kk] = ldb8(qrh + kk * 32);
      ql[kk] = ldb8(qrl + kk * 32);
    }
  }
  f32x4 o[8];
#pragma unroll
  for (int n = 0; n < 8; n++) o[n] = (f32x4){0.f, 0.f, 0.f, 0.f};
  float mr[4] = {-1e30f, -1e30f, -1e30f, -1e30f};
  float lr[4] = {0.f, 0.f, 0.f, 0.f};

  int ktd = q0 >> 6;
  for (int kt = wave; kt <= ktd; kt += 4) {
    f32x4 s[4];
#pragma unroll
    for (int n = 0; n < 4; n++) s[n] = (f32x4){0.f, 0.f, 0.f, 0.f};
#pragma unroll
    for (int n = 0; n < 4; n++) {
      bf16x8 kh[4], kl[4];
#pragma unroll
      for (int kk = 0; kk < 4; kk++) {
        size_t off = (size_t)((kt * 16 + n * 4 + kk) * 64 + lane) * 8;
        kh[kk] = ldb8(Khb + off);
        kl[kk] = ldb8(Klb + off);
      }
#pragma unroll
      for (int kk = 0; kk < 4; kk++) {
        s[n] = __builtin_amdgcn_mfma_f32_16x16x32_bf16(qh[kk], kh[kk], s[n], 0, 0, 0);
        s[n] = __builtin_amdgcn_mfma_f32_16x16x32_bf16(ql[kk], kh[kk], s[n], 0, 0, 0);
        s[n] = __builtin_amdgcn_mfma_f32_16x16x32_bf16(qh[kk], kl[kk], s[n], 0, 0, 0);
      }
    }
    if (kt == ktd) {
#pragma unroll
      for (int n = 0; n < 4; n++) {
        int col = kt * 64 + n * 16 + l15;
#pragma unroll
        for (int r = 0; r < 4; r++)
          if (col > q0 + quad * 4 + r) s[n][r] = -1e30f;
      }
    }
    float mnew[4];
#pragma unroll
    for (int r = 0; r < 4; r++)
      mnew[r] = fmaxf(fmaxf(s[0][r], s[1][r]), fmaxf(s[2][r], s[3][r]));
#pragma unroll
    for (int off = 1; off < 16; off <<= 1)
#pragma unroll
      for (int r = 0; r < 4; r++) mnew[r] = fmaxf(mnew[r], __shfl_xor(mnew[r], off));
    float alpha[4];
#pragma unroll
    for (int r = 0; r < 4; r++) {
      float mi = fmaxf(mr[r], mnew[r]);
      alpha[r] = __expf(mr[r] - mi);
      mr[r] = mi;
    }
    float rs[4];
#pragma unroll
    for (int n = 0; n < 4; n++)
#pragma unroll
      for (int r = 0; r < 4; r++) s[n][r] = __expf(s[n][r] - mr[r]);
#pragma unroll
    for (int r = 0; r < 4; r++) rs[r] = (s[0][r] + s[1][r]) + (s[2][r] + s[3][r]);
#pragma unroll
    for (int off = 1; off < 16; off <<= 1)
#pragma unroll
      for (int r = 0; r < 4; r++) rs[r] += __shfl_xor(rs[r], off);
#pragma unroll
    for (int r = 0; r < 4; r++) lr[r] = lr[r] * alpha[r] + rs[r];
#pragma unroll
    for (int n = 0; n < 8; n++)
#pragma unroll
      for (int r = 0; r < 4; r++) o[n][r] *= alpha[r];
    // P: C-layout -> A-layout via wave-private LDS (lgkm ordering suffices)
    asm volatile("s_waitcnt lgkmcnt(0)" ::: "memory");
#pragma unroll
    for (int n = 0; n < 4; n++)
#pragma unroll
      for (int r = 0; r < 4; r++)
        pbuf[(quad * 4 + r) * PP + n * 16 + l15] = f2bf(s[n][r]);
    asm volatile("s_waitcnt lgkmcnt(0)" ::: "memory");
#pragma unroll
    for (int ks = 0; ks < 2; ks++) {
      bf16x8 pa = ldb8(pbuf + l15 * PP + ks * 32 + quad * 8);
#pragma unroll
      for (int n = 0; n < 8; n++) {
        bf16x8 vf = ldb8(Vb + (size_t)((kt * 16 + ks * 8 + n) * 64 + lane) * 8);
        o[n] = __builtin_amdgcn_mfma_f32_16x16x32_bf16(pa, vf, o[n], 0, 0, 0);
      }
    }
  }

  // ---- cross-wave combine ----
  if (l15 == 0) {
#pragma unroll
    for (int r = 0; r < 4; r++)
      mlbuf[wave * 16 + quad * 4 + r] = make_float2(mr[r], lr[r]);
  }
  __syncthreads();
  float f[4];
#pragma unroll
  for (int r = 0; r < 4; r++) {
    int row = quad * 4 + r;
    float M = mlbuf[row].x;
#pragma unroll
    for (int w2 = 1; w2 < 4; w2++) M = fmaxf(M, mlbuf[w2 * 16 + row].x);
    f[r] = __expf(mr[r] - M);
  }
#pragma unroll
  for (int n = 0; n < 8; n++)
#pragma unroll
    for (int r = 0; r < 4; r++)
      obuf[(size_t)(wave * 16 + quad * 4 + r) * OP + n * 16 + l15] = o[n][r] * f[r];
  __syncthreads();
  int row = wave * 4 + quad;
  int c0 = l15 * 8;
  float M = mlbuf[row].x;
#pragma unroll
  for (int w2 = 1; w2 < 4; w2++) M = fmaxf(M, mlbuf[w2 * 16 + row].x);
  float L = 0.f;
#pragma unroll
  for (int w2 = 0; w2 < 4; w2++)
    L += __expf(mlbuf[w2 * 16 + row].x - M) * mlbuf[w2 * 16 + row].y;
  f32x4 a0 = (f32x4){0.f, 0.f, 0.f, 0.f}, a1 = a0;
#pragma unroll
  for (int w2 = 0; w2 < 4; w2++) {
    const float* src = obuf + (size_t)(w2 * 16 + row) * OP + c0;
    a0 += *(const f32x4*)(const void*)src;
    a1 += *(const f32x4*)(const void*)(src + 4);
  }
  float invL = 1.0f / L;
  float* op = out + ((size_t)b * T_ + q0 + row) * H_ + c0;
  *(f32x4*)(void*)op = a0 * invL;
  *(f32x4*)(void*)(op + 4) = a1 * invL;
}

// ---------------------------------------------------------------------------
extern "C" void kernel_launch(void* const* d_in, const int* in_sizes, int n_in,
                              void* d_out, int out_size, void* d_ws, size_t ws_size,
                              hipStream_t stream) {
  const float* x  = (const float*)d_in[0];
  const float* Wq = (const float*)d_in[1];
  const float* Wk = (const float*)d_in[2];
  const float* Wv = (const float*)d_in[3];
  const size_t BTH = (size_t)B_ * T_ * H_;
  unsigned short* Whi = (unsigned short*)d_ws;   // 3*H*C
  unsigned short* Wlo = Whi + 3 * H_ * C_;       // 2*H*C (Q,K only)
  unsigned short* Vf  = Wlo + 2 * H_ * C_;       // BTH
  unsigned short* Qhi = Vf + BTH;
  unsigned short* Qlo = Qhi + BTH;
  unsigned short* Khf = Qlo + BTH;
  unsigned short* Klf = Khf + BTH;
  float* out = (float*)d_out;

  wt_k<<<dim3(32, 4, 3), dim3(32, 8), 0, stream>>>(Wq, Wk, Wv, Whi, Wlo);
  qkv_k<<<3 * (B_ * T_ / 64), 256, 0, stream>>>(x, Whi, Wlo, Qhi, Qlo, Khf, Klf, Vf);
  flash_k<<<B_ * (T_ / 16), 256, 0, stream>>>(Qhi, Qlo, Khf, Klf, Vf, out);
}